// Round 1
// 89.045 us; speedup vs baseline: 1.0064x; 1.0064x over previous
//
#include <hip/hip_runtime.h>

#define Bb 8
#define Ss 50
#define Ii 20
#define Cc 64
#define Nn 4096
#define MAXM 1024
#define POSB (Ss * Ii)    // 1000

typedef unsigned short ushort_t;
typedef __attribute__((ext_vector_type(8))) short short8;   // 8 bf16 = 4 VGPRs (MFMA A/B frag)
typedef __attribute__((ext_vector_type(4))) float f32x4;    // MFMA C/D frag

__device__ inline ushort_t bf16_rn(float x) {
    unsigned u = __float_as_uint(x);
    u = u + 0x7FFFu + ((u >> 16) & 1u);     // round-to-nearest-even
    return (ushort_t)(u >> 16);
}
__device__ inline float bf16_f(ushort_t h) { return __uint_as_float(((unsigned)h) << 16); }

__device__ inline short8 cvthi8(float4 a, float4 b) {
    short8 r;
    r[0] = (short)bf16_rn(a.x); r[1] = (short)bf16_rn(a.y);
    r[2] = (short)bf16_rn(a.z); r[3] = (short)bf16_rn(a.w);
    r[4] = (short)bf16_rn(b.x); r[5] = (short)bf16_rn(b.y);
    r[6] = (short)bf16_rn(b.z); r[7] = (short)bf16_rn(b.w);
    return r;
}
__device__ inline short8 cvtlo8(float4 a, float4 b, short8 hi) {
    short8 r;
    r[0] = (short)bf16_rn(a.x - bf16_f((ushort_t)hi[0]));
    r[1] = (short)bf16_rn(a.y - bf16_f((ushort_t)hi[1]));
    r[2] = (short)bf16_rn(a.z - bf16_f((ushort_t)hi[2]));
    r[3] = (short)bf16_rn(a.w - bf16_f((ushort_t)hi[3]));
    r[4] = (short)bf16_rn(b.x - bf16_f((ushort_t)hi[4]));
    r[5] = (short)bf16_rn(b.y - bf16_f((ushort_t)hi[5]));
    r[6] = (short)bf16_rn(b.z - bf16_f((ushort_t)hi[6]));
    r[7] = (short)bf16_rn(b.w - bf16_f((ushort_t)hi[7]));
    return r;
}

// ---------------- K1: role-split aux ----------------
// blocks 0..7   : per-batch linked-list build + compact slot assignment (LDS atomics only)
// blocks 8..263 : F = E @ W (fp32, 16 rows each) + cvec = E @ bias
__global__ __launch_bounds__(1024) void aux_kernel(
    const float* __restrict__ input, const int* __restrict__ ids,
    const int* __restrict__ seqlen, const float* __restrict__ E,
    const float* __restrict__ W, const float* __restrict__ bias,
    int* __restrict__ Mcnt, int* __restrict__ slotHead, int* __restrict__ gnext,
    float* __restrict__ cvec, float* __restrict__ Fbuf) {
    __shared__ int smem[5120];            // 20 KB, aliased per role
    int tid = threadIdx.x;

    if (blockIdx.x < Bb) {
        int b = blockIdx.x;
        int* head = smem;                 // 4096
        __shared__ int mcnt;
        for (int i = tid; i < Nn; i += 1024) head[i] = -1;
        if (tid == 0) mcnt = 0;
        __syncthreads();
        int P = seqlen[b] * Ii;           // masked positions are exactly p < P
        if (tid < P) {
            int id = ids[b * POSB + tid];
            gnext[b * POSB + tid] = atomicExch(&head[id], tid);
        }
        __syncthreads();
        for (int i = tid; i < Nn; i += 1024) {
            int h = head[i];
            if (h >= 0) slotHead[b * MAXM + atomicAdd(&mcnt, 1)] = h;
        }
        __syncthreads();
        if (tid == 0) Mcnt[b] = mcnt;
    } else {
        int pb = blockIdx.x - Bb;
        float* wlds = (float*)smem;             // 4096 floats
        float* elds = (float*)smem + 4096;      // 1024 floats
        int n0 = pb * 16;
#pragma unroll
        for (int i = 0; i < 4; i++) wlds[tid + 1024 * i] = W[tid + 1024 * i];
        float ev = E[(size_t)n0 * Cc + tid];
        elds[tid] = ev;
        __syncthreads();
        int nl = tid >> 6, k = tid & 63;
        float acc = 0.f;
#pragma unroll
        for (int c = 0; c < Cc; c++) acc = fmaf(elds[nl * Cc + c], wlds[c * Cc + k], acc);
        Fbuf[(size_t)(n0 + nl) * Cc + k] = acc;
        float p = ev * bias[k];
#pragma unroll
        for (int off = 32; off; off >>= 1) p += __shfl_down(p, off);
        if (k == 0) cvec[n0 + nl] = p;
    }
}

// ---------------- K2: mean gather — one wave per slot, bf16-hi output only ----------------
__global__ __launch_bounds__(256) void mean_kernel(
    const float* __restrict__ input, const int* __restrict__ slotHead,
    const int* __restrict__ gnext, const int* __restrict__ Mcnt,
    ushort_t* __restrict__ Mhi) {
    int w = (blockIdx.x * 256 + threadIdx.x) >> 6;
    int lane = threadIdx.x & 63;
    int b = w >> 10;
    int slot = w & (MAXM - 1);
    if (slot >= Mcnt[b]) return;          // wave-uniform
    int p = slotHead[b * MAXM + slot];
    float sum = 0.f; int k = 0;
    while (p >= 0) {
        sum += input[((size_t)(b * POSB + p)) * Cc + lane];
        k++;
        p = gnext[b * POSB + p];
    }
    Mhi[((size_t)(b * MAXM + slot)) * Cc + lane] = bf16_rn(sum / (float)k);
}

#define MFMA(A, B, C) __builtin_amdgcn_mfma_f32_16x16x32_bf16(A, B, C, 0, 0, 0)

// ---------------- K3: MFMA scores + max-free softmax + combine ----------------
// block = (b, 64-n tile); 8 waves = 4 n-subtiles x 2 m-halves (stride-2 m-tiles).
// Scores are provably tiny (|s| <~ 1 << 88): exp() needs NO running-max tracking,
// so the per-tile softmax update is pure {leaky, exp, cndmask-tail, add, fma} and
// the wave/kq/m-half merges are plain sums.
// S hi-only (constant-shift part cancels in softmax); D hi + F-lo (F-side error
// is fixed per n and would reach ~9e-4 without the lo term; mean-side lo averages away).
__global__ __launch_bounds__(512) void main_kernel(
    const float* __restrict__ E, const float* __restrict__ Fbuf,
    const ushort_t* __restrict__ Mhi,
    const int* __restrict__ Mcnt, const float* __restrict__ cvec,
    float* __restrict__ out) {
    __shared__ float part[2][64];        // [l|av][n] partial from m-half 1
    int idx = blockIdx.x;
    int ntile = idx >> 3;
    int b = (idx + (idx >> 3) + (idx >> 8)) & 7;   // batch mix across CU round-robin
    int tid = threadIdx.x;
    int wave = tid >> 6, lane = tid & 63;
    int wn = wave & 3, wm = wave >> 2;             // n-subtile / m-half
    int kq = lane >> 4;                            // 0..3 (K-subgroup / C-row group)
    int n = ntile * 64 + wn * 16 + (lane & 15);

    // B-operand frags: convert fp32 E/F rows inline (no reuse across blocks)
    const float4* ep = (const float4*)(E + (size_t)n * Cc + kq * 8);
    const float4* fp = (const float4*)(Fbuf + (size_t)n * Cc + kq * 8);
    float4 ea = ep[0], eb = ep[1], ec = ep[8], ed = ep[9];   // +8 float4 = +32 floats
    float4 fa = fp[0], fb = fp[1], fc = fp[8], fd = fp[9];
    short8 Eh0 = cvthi8(ea, eb), Eh1 = cvthi8(ec, ed);
    short8 Fh0 = cvthi8(fa, fb), Fh1 = cvthi8(fc, fd);
    short8 Fl0 = cvtlo8(fa, fb, Fh0), Fl1 = cvtlo8(fc, fd, Fh1);

    int M = Mcnt[b];
    int nmt = (M + 15) >> 4;
    size_t ab = ((size_t)(b * MAXM) + (lane & 15)) * Cc + kq * 8;

    // prefetch A-frags for this wave's first m-tile (rows < MAXM always: safe)
    size_t a0 = ab + (size_t)wm * (16 * Cc);
    short8 Ah0 = *(const short8*)(Mhi + a0), Ah1 = *(const short8*)(Mhi + a0 + 32);

    float l = 0.f, av = 0.f;
    int rowg = kq * 4;

#pragma unroll 1
    for (int mt = wm; mt < nmt; mt += 2) {
        int mtn = (mt + 2 < nmt) ? mt + 2 : mt;
        size_t an = ab + (size_t)mtn * (16 * Cc);
        short8 Nh0 = *(const short8*)(Mhi + an), Nh1 = *(const short8*)(Mhi + an + 32);

        f32x4 S = {0.f, 0.f, 0.f, 0.f}, D = {0.f, 0.f, 0.f, 0.f};
        S = MFMA(Ah0, Eh0, S); S = MFMA(Ah1, Eh1, S);
        D = MFMA(Ah0, Fh0, D); D = MFMA(Ah1, Fh1, D);
        D = MFMA(Ah0, Fl0, D); D = MFMA(Ah1, Fl1, D);

        int mrow = mt * 16 + rowg;
#pragma unroll
        for (int r = 0; r < 4; r++) {
            float s = S[r];
            float sc = fmaxf(s, 0.2f * s);         // leaky_relu 0.2, branchless
            float ex = __expf(sc);                 // no max-shift needed: |sc| <= ~1
            ex = (mrow + r < M) ? ex : 0.f;        // tail guard, branchless
            l += ex;
            av = fmaf(ex, D[r], av);
        }
        Ah0 = Nh0; Ah1 = Nh1;
    }

    // sum the 4 row-groups sharing column n (lanes xor 16, 32) — plain sums
#pragma unroll
    for (int mask = 16; mask <= 32; mask <<= 1) {
        l  += __shfl_xor(l,  mask);
        av += __shfl_xor(av, mask);
    }
    // merge the two m-halves through LDS
    if (wm == 1 && lane < 16) {
        part[0][wn * 16 + lane] = l;
        part[1][wn * 16 + lane] = av;
    }
    __syncthreads();
    if (wm == 0 && lane < 16) {
        float lp  = part[0][wn * 16 + lane];
        float avp = part[1][wn * 16 + lane];
        out[b * Nn + n] = (av + avp) / (l + lp) + cvec[n];
    }
}

extern "C" void kernel_launch(void* const* d_in, const int* in_sizes, int n_in,
                              void* d_out, int out_size, void* d_ws, size_t ws_size,
                              hipStream_t stream) {
    (void)in_sizes; (void)n_in; (void)out_size; (void)ws_size;
    const float* input  = (const float*)d_in[0];
    const float* E      = (const float*)d_in[1];
    const float* W      = (const float*)d_in[2];
    const float* bias   = (const float*)d_in[3];
    const int*   ids    = (const int*)d_in[4];
    const int*   seqlen = (const int*)d_in[5];
    float* out = (float*)d_out;

    int*      Mcnt     = (int*)d_ws;                        // 16
    int*      slotHead = Mcnt + 16;                         // B*MAXM
    int*      gnext    = slotHead + Bb * MAXM;              // B*POSB
    float*    cvec     = (float*)(gnext + Bb * POSB);       // N
    float*    Fbuf     = cvec + Nn;                         // N*C fp32
    ushort_t* Mhi      = (ushort_t*)(Fbuf + (size_t)Nn * Cc);  // B*MAXM*C bf16

    aux_kernel <<<Bb + Nn / 16, 1024, 0, stream>>>(input, ids, seqlen, E, W, bias,
                                                   Mcnt, slotHead, gnext, cvec, Fbuf);
    mean_kernel<<<Bb * MAXM / 4, 256, 0, stream>>>(input, slotHead, gnext, Mcnt, Mhi);
    main_kernel<<<Bb * (Nn / 64), 512, 0, stream>>>(E, Fbuf, Mhi, Mcnt, cvec, out);
}